// Round 23
// baseline (183.922 us; speedup 1.0000x reference)
//
#include <hip/hip_runtime.h>

#define NROW 8192
#define INF  512
#define OUTF 256
#define M_ELEM (NROW * OUTF)   // 2,097,152 f32 per output matrix
#define NSTEP 64               // K-steps of 128

typedef __bf16 v8bf __attribute__((ext_vector_type(8)));
typedef __bf16 v4bf __attribute__((ext_vector_type(4)));
typedef float  v4f  __attribute__((ext_vector_type(4)));
typedef float  v2f  __attribute__((ext_vector_type(2)));

__device__ __forceinline__ v8bf cvt_bf8(v4f u0, v4f u1) {
  v8bf v;
  v[0]=(__bf16)u0[0]; v[1]=(__bf16)u0[1]; v[2]=(__bf16)u0[2]; v[3]=(__bf16)u0[3];
  v[4]=(__bf16)u1[0]; v[5]=(__bf16)u1[1]; v[6]=(__bf16)u1[2]; v[7]=(__bf16)u1[3];
  return v;
}

// ---------------------------------------------------------------------------
// Kernel A: seq = feat @ W^T, bf16 MFMA, output in B-fragment-packed layout:
//   elem(m,o) -> (((m>>5)*16 + (o>>4))*64 + ((m>>3)&3)*16 + (o&15))*8 + (m&7)
// BM=32 -> 256 blocks (1/CU) for full-chip coverage.
// ---------------------------------------------------------------------------
__global__ __launch_bounds__(256) void seq_fts_kernel(
    const float* __restrict__ feat, const float* __restrict__ W,
    __bf16* __restrict__ Bp) {
  const int tid  = threadIdx.x;
  const int lane = tid & 63, w = tid >> 6;
  const int llo  = lane & 15, lhi = lane >> 4;
  const int row0 = blockIdx.x * 32;
  const int col0 = w * 64;

  v4f acc[2][4] = {};
#pragma unroll 1
  for (int kb = 0; kb < INF / 32; ++kb) {
    const int kofs = kb * 32 + lhi * 8;
    v8bf a[2], b[4];
#pragma unroll
    for (int i = 0; i < 2; ++i) {
      const float* p = feat + (size_t)(row0 + i * 16 + llo) * INF + kofs;
      a[i] = cvt_bf8(*(const v4f*)p, *(const v4f*)(p + 4));
    }
#pragma unroll
    for (int i = 0; i < 4; ++i) {
      const float* p = W + (size_t)(col0 + i * 16 + llo) * INF + kofs;
      b[i] = cvt_bf8(*(const v4f*)p, *(const v4f*)(p + 4));
    }
#pragma unroll
    for (int ri = 0; ri < 2; ++ri)
#pragma unroll
      for (int ci = 0; ci < 4; ++ci)
        acc[ri][ci] = __builtin_amdgcn_mfma_f32_16x16x32_bf16(
            a[ri], b[ci], acc[ri][ci], 0, 0, 0);
  }
#pragma unroll
  for (int ri = 0; ri < 2; ++ri)
#pragma unroll
    for (int ci = 0; ci < 4; ++ci) {
      const int mf = row0 + ri * 16 + lhi * 4;
      const int o  = col0 + ci * 16 + llo;
      size_t e = (((size_t)(mf >> 5) * 16 + (o >> 4)) * 64 +
                  ((mf >> 3) & 3) * 16 + (o & 15)) * 8 + (mf & 7);
      v4bf v;
      v[0] = (__bf16)acc[ri][ci][0]; v[1] = (__bf16)acc[ri][ci][1];
      v[2] = (__bf16)acc[ri][ci][2]; v[3] = (__bf16)acc[ri][ci][3];
      *(v4bf*)(Bp + e) = v;
    }
}

// ---------------------------------------------------------------------------
// Kernel B: out = prelu(adj @ seq + bias).
// TWO-STEP-DEEP prefetch with COMPILER-PRECISE waits (zero manual vmcnt):
// A(t+2)/B(t+2) live in named register sets; write_a consumes only
// aSet[(t+1)&1], so the compiler's register-dependency wait is COUNTED
// (newer prefetches stay in flight). Rotation enforced by dataflow, not
// instruction order -> nothing for codegen to defeat. Flight ~1.7 steps
// (~4-5k cy) >> loaded latency. Live set ~116 VGPR (allocator-friendly):
// aSet 2x8, bSet 2x32, acc 16, addr ~20. BM=32, BK=128 (512 B extents),
// 8 waves col-dedup'd (32 cols/wave), LDS 2x16 KB -> 2 blocks/CU.
// Step u: [issue A(u+2)] [compute buf(u&1), B(u)] [issue B(u+2)]
//         [write_a buf((u+1)&1) <- A(u+1)] [lgkm, barrier]
// ---------------------------------------------------------------------------
__global__ __launch_bounds__(512, 2) void gcn_agg_kernel(
    const float* __restrict__ adjA, const float* __restrict__ adjB,
    const __bf16* __restrict__ Bp, const float* __restrict__ bias,
    const float* __restrict__ prelu_a, float* __restrict__ out) {
  const int tid  = threadIdx.x;
  const int lane = tid & 63, w = tid >> 6;   // wave w -> cols [w*32, w*32+32)
  const int llo  = lane & 15, lhi = lane >> 4;
  const int row0 = blockIdx.x * 32;
  const int z    = blockIdx.y;
  const float* __restrict__ adj = z ? adjB : adjA;

  __shared__ __align__(16) char LdsA[2][16384];   // 2 x (32 rows x 512 B)

  v4f acc[2][2] = {};        // 16 VGPR

  // --- A: 4 rows/wave, one 512 B extent per row (v2f per lane, NT).
  v2f aS0[4], aS1[4];        // two named A sets, 8 VGPR each
  auto issue_a = [&](int t, v2f (&ar)[4]) {
#pragma unroll
    for (int i = 0; i < 4; ++i) {
      const int r = w * 4 + i;
      const float* src =
          adj + (size_t)(row0 + r) * NROW + t * 128 + (lane << 1);
      ar[i] = __builtin_nontemporal_load((const v2f*)src);
    }
  };
  // swizzled write: lane l's 8 B -> row r, 16B-slot ((l>>1)^key), half (l&1).
  auto write_a = [&](int buf, v2f (&ar)[4]) {
#pragma unroll
    for (int i = 0; i < 4; ++i) {
      const int r   = w * 4 + i;
      const int key = ((r & 15) << 1) | ((r >> 3) & 1);
      const int byt = r * 512 + ((((lane >> 1) ^ key) << 4) | ((lane & 1) << 3));
      *(v2f*)(&LdsA[buf][byt]) = ar[i];
    }
  };

  // --- B: [4 kg][2 ci] = 32 VGPR per set (col-dedup'd).
  const __bf16* __restrict__ Bpw = Bp + ((size_t)(w * 2) * 64 + lane) * 8;
  v8bf bS0[4][2], bS1[4][2];
  auto issue_b = [&](int t, v8bf (&b)[4][2]) {
#pragma unroll
    for (int g = 0; g < 4; ++g)
#pragma unroll
      for (int ci = 0; ci < 2; ++ci)
        b[g][ci] = *(const v8bf*)(
            Bpw + ((size_t)((t * 4 + g) * 16 + ci)) * 512);
  };

  auto compute = [&](int buf, v8bf (&b)[4][2]) {
    const char* ab = &LdsA[buf][0];
#pragma unroll
    for (int kg = 0; kg < 4; ++kg) {
      v8bf af[2];
#pragma unroll
      for (int rt = 0; rt < 2; ++rt) {
        const int r   = rt * 16 + llo;
        const int key = ((r & 15) << 1) | ((r >> 3) & 1);
        const char* base = ab + r * 512;
        const int s0 = kg * 8 + lhi * 2;
        v4f u0 = *(const v4f*)(base + (((s0    ) ^ key) << 4));
        v4f u1 = *(const v4f*)(base + (((s0 + 1) ^ key) << 4));
        af[rt] = cvt_bf8(u0, u1);
      }
#pragma unroll
      for (int ci = 0; ci < 2; ++ci)
#pragma unroll
        for (int rt = 0; rt < 2; ++rt)
          acc[rt][ci] = __builtin_amdgcn_mfma_f32_16x16x32_bf16(
              af[rt], b[kg][ci], acc[rt][ci], 0, 0, 0);
    }
  };

  // prologue: A(0)->aS0 (write buf0), B(0)->bS0, A(1)->aS1, B(1)->bS1.
  issue_a(0, aS0);
  issue_b(0, bS0);
  issue_a(1, aS1);
  issue_b(1, bS1);
  write_a(0, aS0);   // compiler waits only aS0; b0/a1/b1 stay in flight
  asm volatile("s_waitcnt lgkmcnt(0)" ::: "memory");
  __builtin_amdgcn_s_barrier();

#pragma unroll 1
  for (int u = 0; u < NSTEP; u += 2) {
    // ---- even step u: buf0 + bS0; aS0 free -> A(u+2); bS0 freed -> B(u+2)
    if (u + 2 < NSTEP) issue_a(u + 2, aS0);
    compute(0, bS0);                     // waits bS0 only (landed long ago)
    if (u + 2 < NSTEP) issue_b(u + 2, bS0);
    write_a(1, aS1);                     // waits aS1 only (counted, precise)
    asm volatile("s_waitcnt lgkmcnt(0)" ::: "memory");
    __builtin_amdgcn_s_barrier();
    // ---- odd step u+1: buf1 + bS1; aS1 free -> A(u+3); bS1 -> B(u+3)
    if (u + 3 < NSTEP) issue_a(u + 3, aS1);
    compute(1, bS1);
    if (u + 3 < NSTEP) issue_b(u + 3, bS1);
    if (u + 2 < NSTEP) {
      write_a(0, aS0);                   // A(u+2), issued one step ago
      asm volatile("s_waitcnt lgkmcnt(0)" ::: "memory");
    }
    __builtin_amdgcn_s_barrier();
  }

  // epilogue: bias + prelu, direct store
  const float slope = prelu_a[0];
  float* __restrict__ outp = out + (size_t)z * M_ELEM;
#pragma unroll
  for (int ci = 0; ci < 2; ++ci) {
    const int o  = w * 32 + ci * 16 + llo;
    const float bs = bias[o];
#pragma unroll
    for (int rt = 0; rt < 2; ++rt) {
      const int m = row0 + rt * 16 + lhi * 4;
#pragma unroll
      for (int r = 0; r < 4; ++r) {
        float v = acc[rt][ci][r] + bs;
        outp[(size_t)(m + r) * OUTF + o] = v >= 0.f ? v : slope * v;
      }
    }
  }
}

extern "C" void kernel_launch(void* const* d_in, const int* in_sizes, int n_in,
                              void* d_out, int out_size, void* d_ws, size_t ws_size,
                              hipStream_t stream) {
  const float* feat = (const float*)d_in[0];
  const float* adj  = (const float*)d_in[1];
  const float* aug  = (const float*)d_in[2];
  const float* W    = (const float*)d_in[3];
  const float* bias = (const float*)d_in[4];
  const float* pa   = (const float*)d_in[5];
  float* out = (float*)d_out;
  __bf16* Bp = (__bf16*)d_ws;                    // 4 MB packed seq_fts

  seq_fts_kernel<<<dim3(NROW / 32), 256, 0, stream>>>(feat, W, Bp);
  gcn_agg_kernel<<<dim3(NROW / 32, 2), 512, 0, stream>>>(
      adj, aug, Bp, bias, pa, out);
}

// Round 24
// 169.322 us; speedup vs baseline: 1.0862x; 1.0862x over previous
//
#include <hip/hip_runtime.h>

#define NROW 8192
#define INF  512
#define OUTF 256
#define M_ELEM (NROW * OUTF)   // 2,097,152 f32 per output matrix
#define NSTEP 32               // K-steps of 256

typedef __bf16 v8bf __attribute__((ext_vector_type(8)));
typedef __bf16 v4bf __attribute__((ext_vector_type(4)));
typedef float  v4f  __attribute__((ext_vector_type(4)));

__device__ __forceinline__ v8bf cvt_bf8(v4f u0, v4f u1) {
  v8bf v;
  v[0]=(__bf16)u0[0]; v[1]=(__bf16)u0[1]; v[2]=(__bf16)u0[2]; v[3]=(__bf16)u0[3];
  v[4]=(__bf16)u1[0]; v[5]=(__bf16)u1[1]; v[6]=(__bf16)u1[2]; v[7]=(__bf16)u1[3];
  return v;
}

// ---------------------------------------------------------------------------
// Kernel A: seq = feat @ W^T, bf16 MFMA, output in B-fragment-packed layout:
//   elem(m,o) -> (((m>>5)*16 + (o>>4))*64 + ((m>>3)&3)*16 + (o&15))*8 + (m&7)
// ---------------------------------------------------------------------------
__global__ __launch_bounds__(256) void seq_fts_kernel(
    const float* __restrict__ feat, const float* __restrict__ W,
    __bf16* __restrict__ Bp) {
  const int tid  = threadIdx.x;
  const int lane = tid & 63, w = tid >> 6;
  const int llo  = lane & 15, lhi = lane >> 4;
  const int row0 = blockIdx.x * 64;
  const int col0 = w * 64;

  v4f acc[4][4] = {};
#pragma unroll 1
  for (int kb = 0; kb < INF / 32; ++kb) {
    const int kofs = kb * 32 + lhi * 8;
    v8bf a[4], b[4];
#pragma unroll
    for (int i = 0; i < 4; ++i) {
      const float* p = feat + (size_t)(row0 + i * 16 + llo) * INF + kofs;
      a[i] = cvt_bf8(*(const v4f*)p, *(const v4f*)(p + 4));
    }
#pragma unroll
    for (int i = 0; i < 4; ++i) {
      const float* p = W + (size_t)(col0 + i * 16 + llo) * INF + kofs;
      b[i] = cvt_bf8(*(const v4f*)p, *(const v4f*)(p + 4));
    }
#pragma unroll
    for (int ri = 0; ri < 4; ++ri)
#pragma unroll
      for (int ci = 0; ci < 4; ++ci)
        acc[ri][ci] = __builtin_amdgcn_mfma_f32_16x16x32_bf16(
            a[ri], b[ci], acc[ri][ci], 0, 0, 0);
  }
#pragma unroll
  for (int ri = 0; ri < 4; ++ri)
#pragma unroll
    for (int ci = 0; ci < 4; ++ci) {
      const int mf = row0 + ri * 16 + lhi * 4;
      const int o  = col0 + ci * 16 + llo;
      size_t e = (((size_t)(mf >> 5) * 16 + (o >> 4)) * 64 +
                  ((mf >> 3) & 3) * 16 + (o & 15)) * 8 + (mf & 7);
      v4bf v;
      v[0] = (__bf16)acc[ri][ci][0]; v[1] = (__bf16)acc[ri][ci][1];
      v[2] = (__bf16)acc[ri][ci][2]; v[3] = (__bf16)acc[ri][ci][3];
      *(v4bf*)(Bp + e) = v;
    }
}

// ---------------------------------------------------------------------------
// Kernel B: out = prelu(adj @ seq + bias).
// DMA-DEPTH pipeline, allocator-immune: A staged via global_load_lds (depth
// lives in the DMA queue + fixed LDS buffers -- the compiler cannot rename
// or sink it), 1 KB contiguous extents (R9's granularity win), COUNTED
// vmcnt only (never 0 in the loop; R9..R12's per-step vmcnt(0) drain was
// the burst-and-drain killer). B cross-step double-buffered in regs at the
// 32-VGPR set size R22 proved survives codegen.
// Per-wave FIFO per step t (steady state, verified by hand):
//   [A(t+1)x8] -> compute(bX=B(2t)): compiler waits vmcnt(16)  (A alive)
//   issue B(2t+2)->bX ; compute(bY=B(2t+1)): vmcnt(16)          (A alive)
//   issue B(2t+3)->bY ; barrier ; issue A(t+2)->buf[p] (8 DMA)
//   vmcnt(24): retires exactly A(t+1); leaves bX,bY,A(t+2) in flight
//   barrier ; p^=1.
// Tail: clamped duplicate issues keep the FIFO loop-invariant.
// ---------------------------------------------------------------------------
__global__ __launch_bounds__(512, 1) void gcn_agg_kernel(
    const float* __restrict__ adjA, const float* __restrict__ adjB,
    const __bf16* __restrict__ Bp, const float* __restrict__ bias,
    const float* __restrict__ prelu_a, float* __restrict__ out) {
  const int tid  = threadIdx.x;
  const int lane = tid & 63, w = tid >> 6;   // wave w -> cols [w*32, w*32+32)
  const int llo  = lane & 15, lhi = lane >> 4;
  const int row0 = blockIdx.x * 64;
  const int z    = blockIdx.y;
  const float* __restrict__ adj = z ? adjB : adjA;

  __shared__ __align__(16) char LdsA[2][65536];   // 2 x (64 rows x 1 KB)

  v4f acc[4][2] = {};        // 32 VGPR

  // --- A staging via DMA: 8 instr/wave, each = one row's 1 KB extent.
  // LDS row r slot p holds source slot p ^ key(r)  (pre-swizzled source).
  auto stage_a = [&](int buf, int t) {
#pragma unroll
    for (int i = 0; i < 8; ++i) {
      const int r   = w * 8 + i;
      const int key = ((r & 15) << 1) | ((r >> 3) & 1);
      const float* src =
          adj + (size_t)(row0 + r) * NROW + t * 256 + ((lane ^ key) << 2);
      __builtin_amdgcn_global_load_lds(
          (const __attribute__((address_space(1))) void*)src,
          (__attribute__((address_space(3))) void*)(&LdsA[buf][r * 1024]),
          16, 0, 2 /* NT: zero-reuse stream */);
    }
  };

  // --- B half-tile: [4 kg][2 ci] = 32 VGPR per set (col-dedup'd).
  const __bf16* __restrict__ Bpw = Bp + ((size_t)(w * 2) * 64 + lane) * 8;
  auto issue_b = [&](int half, v8bf (&b)[4][2]) {      // half = 2t+h
#pragma unroll
    for (int g = 0; g < 4; ++g)
#pragma unroll
      for (int ci = 0; ci < 2; ++ci)
        b[g][ci] = *(const v8bf*)(
            Bpw + ((size_t)((half * 4 + g) * 16 + ci)) * 512);
  };

  auto compute_half = [&](int buf, int h, v8bf (&b)[4][2]) {
    const char* ab = &LdsA[buf][0];
#pragma unroll
    for (int g = 0; g < 4; ++g) {
      const int kg = h * 4 + g;
      v8bf af[4];
#pragma unroll
      for (int rt = 0; rt < 4; ++rt) {
        const int r   = rt * 16 + llo;
        const int key = ((r & 15) << 1) | ((r >> 3) & 1);
        const char* base = ab + r * 1024;
        v4f u0 = *(const v4f*)(base + (((kg * 8 + lhi * 2    ) ^ key) << 4));
        v4f u1 = *(const v4f*)(base + (((kg * 8 + lhi * 2 + 1) ^ key) << 4));
        af[rt] = cvt_bf8(u0, u1);
      }
#pragma unroll
      for (int ci = 0; ci < 2; ++ci)
#pragma unroll
        for (int rt = 0; rt < 4; ++rt)
          acc[rt][ci] = __builtin_amdgcn_mfma_f32_16x16x32_bf16(
              af[rt], b[g][ci], acc[rt][ci], 0, 0, 0);
    }
  };

  v8bf bX[4][2], bY[4][2];

  // prologue -- FIFO: [A(0)x8, bX(0)x8, bY(1)x8, A(1)x8]; vmcnt(24)
  // retires A(0) only; everything newer stays in flight.
  stage_a(0, 0);
  issue_b(0, bX);
  __builtin_amdgcn_sched_barrier(0);
  issue_b(1, bY);
  __builtin_amdgcn_sched_barrier(0);
  stage_a(1, 1);
  asm volatile("s_waitcnt vmcnt(24)" ::: "memory");
  __builtin_amdgcn_sched_barrier(0);
  __builtin_amdgcn_s_barrier();

#pragma unroll 1
  for (int t = 0; t < NSTEP; ++t) {
    const int p = t & 1;
    compute_half(p, 0, bX);                 // compiler: vmcnt(16), A alive
    __builtin_amdgcn_sched_barrier(0);
    {
      const int hb = (2 * t + 2 < 2 * NSTEP) ? 2 * t + 2 : 2 * NSTEP - 2;
      issue_b(hb, bX);                      // reuse after last use
    }
    __builtin_amdgcn_sched_barrier(0);
    compute_half(p, 1, bY);                 // compiler: vmcnt(16), A alive
    __builtin_amdgcn_sched_barrier(0);
    {
      const int hb = (2 * t + 3 < 2 * NSTEP) ? 2 * t + 3 : 2 * NSTEP - 1;
      issue_b(hb, bY);
    }
    __builtin_amdgcn_sched_barrier(0);
    __builtin_amdgcn_s_barrier();           // buf[p] fully consumed
    {
      const int ta = (t + 2 < NSTEP) ? t + 2 : NSTEP - 1;  // clamped dup
      stage_a(p, ta);                       // 8 DMA into freed buf[p]
    }
    // retire exactly A(t+1): leaves bX', bY', A(t+2) (24 ops) in flight
    asm volatile("s_waitcnt vmcnt(24)" ::: "memory");
    __builtin_amdgcn_sched_barrier(0);
    __builtin_amdgcn_s_barrier();           // buf[p^1] ready
  }
  asm volatile("s_waitcnt vmcnt(0)" ::: "memory");  // retire clamped dups

  // epilogue: bias + prelu, direct store
  const float slope = prelu_a[0];
  float* __restrict__ outp = out + (size_t)z * M_ELEM;
#pragma unroll
  for (int ci = 0; ci < 2; ++ci) {
    const int o  = w * 32 + ci * 16 + llo;
    const float bs = bias[o];
#pragma unroll
    for (int rt = 0; rt < 4; ++rt) {
      const int m = row0 + rt * 16 + lhi * 4;
#pragma unroll
      for (int r = 0; r < 4; ++r) {
        float v = acc[rt][ci][r] + bs;
        outp[(size_t)(m + r) * OUTF + o] = v >= 0.f ? v : slope * v;
      }
    }
  }
}

extern "C" void kernel_launch(void* const* d_in, const int* in_sizes, int n_in,
                              void* d_out, int out_size, void* d_ws, size_t ws_size,
                              hipStream_t stream) {
  const float* feat = (const float*)d_in[0];
  const float* adj  = (const float*)d_in[1];
  const float* aug  = (const float*)d_in[2];
  const float* W    = (const float*)d_in[3];
  const float* bias = (const float*)d_in[4];
  const float* pa   = (const float*)d_in[5];
  float* out = (float*)d_out;
  __bf16* Bp = (__bf16*)d_ws;                    // 4 MB packed seq_fts

  seq_fts_kernel<<<dim3(NROW / 64), 256, 0, stream>>>(feat, W, Bp);
  gcn_agg_kernel<<<dim3(NROW / 64, 2), 512, 0, stream>>>(
      adj, aug, Bp, bias, pa, out);
}

// Round 25
// 169.284 us; speedup vs baseline: 1.0865x; 1.0002x over previous
//
#include <hip/hip_runtime.h>

#define NROW 8192
#define INF  512
#define OUTF 256
#define M_ELEM (NROW * OUTF)   // 2,097,152 f32 per output matrix
#define NSTEP 32               // K-steps of 256

typedef __bf16 v8bf __attribute__((ext_vector_type(8)));
typedef __bf16 v4bf __attribute__((ext_vector_type(4)));
typedef float  v4f  __attribute__((ext_vector_type(4)));

__device__ __forceinline__ v8bf cvt_bf8(v4f u0, v4f u1) {
  v8bf v;
  v[0]=(__bf16)u0[0]; v[1]=(__bf16)u0[1]; v[2]=(__bf16)u0[2]; v[3]=(__bf16)u0[3];
  v[4]=(__bf16)u1[0]; v[5]=(__bf16)u1[1]; v[6]=(__bf16)u1[2]; v[7]=(__bf16)u1[3];
  return v;
}

// ---------------------------------------------------------------------------
// Kernel A: seq = feat @ W^T, bf16 MFMA, output in B-fragment-packed layout:
//   elem(m,o) -> (((m>>5)*16 + (o>>4))*64 + ((m>>3)&3)*16 + (o&15))*8 + (m&7)
// ---------------------------------------------------------------------------
__global__ __launch_bounds__(256) void seq_fts_kernel(
    const float* __restrict__ feat, const float* __restrict__ W,
    __bf16* __restrict__ Bp) {
  const int tid  = threadIdx.x;
  const int lane = tid & 63, w = tid >> 6;
  const int llo  = lane & 15, lhi = lane >> 4;
  const int row0 = blockIdx.x * 64;
  const int col0 = w * 64;

  v4f acc[4][4] = {};
#pragma unroll 1
  for (int kb = 0; kb < INF / 32; ++kb) {
    const int kofs = kb * 32 + lhi * 8;
    v8bf a[4], b[4];
#pragma unroll
    for (int i = 0; i < 4; ++i) {
      const float* p = feat + (size_t)(row0 + i * 16 + llo) * INF + kofs;
      a[i] = cvt_bf8(*(const v4f*)p, *(const v4f*)(p + 4));
    }
#pragma unroll
    for (int i = 0; i < 4; ++i) {
      const float* p = W + (size_t)(col0 + i * 16 + llo) * INF + kofs;
      b[i] = cvt_bf8(*(const v4f*)p, *(const v4f*)(p + 4));
    }
#pragma unroll
    for (int ri = 0; ri < 4; ++ri)
#pragma unroll
      for (int ci = 0; ci < 4; ++ci)
        acc[ri][ci] = __builtin_amdgcn_mfma_f32_16x16x32_bf16(
            a[ri], b[ci], acc[ri][ci], 0, 0, 0);
  }
#pragma unroll
  for (int ri = 0; ri < 4; ++ri)
#pragma unroll
    for (int ci = 0; ci < 4; ++ci) {
      const int mf = row0 + ri * 16 + lhi * 4;
      const int o  = col0 + ci * 16 + llo;
      size_t e = (((size_t)(mf >> 5) * 16 + (o >> 4)) * 64 +
                  ((mf >> 3) & 3) * 16 + (o & 15)) * 8 + (mf & 7);
      v4bf v;
      v[0] = (__bf16)acc[ri][ci][0]; v[1] = (__bf16)acc[ri][ci][1];
      v[2] = (__bf16)acc[ri][ci][2]; v[3] = (__bf16)acc[ri][ci][3];
      *(v4bf*)(Bp + e) = v;
    }
}

// ---------------------------------------------------------------------------
// Kernel B: out = prelu(adj @ seq + bias).
// HYBRID A staging -- R24's DMA pipeline is latency-covered but pinned at
// the global_load_lds HBM-cold service rate (~6 B/cy/CU). Split each wave's
// 8 A-rows across BOTH memory pipes: rows 0-3 via DMA (depth-2, as R24),
// rows 4-7 via a 16-VGPR reg set (the size R17/R22 proved survives the
// allocator), issued at step top and ds_written at step end (flight = the
// whole compute phase). If the two pipes have separate service budgets,
// A's fill rate ~doubles. One counted vmcnt(20)/step (retires exactly
// A(t+1)'s dma+reg halves; bX',bY',dmaA(t+2) stay in flight); never 0.
// FIFO/step t: [regA(t+1)x4][compute bX][bX'x8][compute bY][bY'x8][barrier]
//   [dmaA(t+2)x4][vmcnt(20)][ds_write regA -> buf[p^1] rows4-7][lgkm][barrier]
// ---------------------------------------------------------------------------
__global__ __launch_bounds__(512, 1) void gcn_agg_kernel(
    const float* __restrict__ adjA, const float* __restrict__ adjB,
    const __bf16* __restrict__ Bp, const float* __restrict__ bias,
    const float* __restrict__ prelu_a, float* __restrict__ out) {
  const int tid  = threadIdx.x;
  const int lane = tid & 63, w = tid >> 6;   // wave w -> cols [w*32, w*32+32)
  const int llo  = lane & 15, lhi = lane >> 4;
  const int row0 = blockIdx.x * 64;
  const int z    = blockIdx.y;
  const float* __restrict__ adj = z ? adjB : adjA;

  __shared__ __align__(16) char LdsA[2][65536];   // 2 x (64 rows x 1 KB)

  v4f acc[4][2] = {};        // 32 VGPR

  // --- A dma half: rows 0..3 of the wave's 8; 1 KB extent, pre-swizzled src.
  auto stage_a_dma = [&](int buf, int t) {
#pragma unroll
    for (int i = 0; i < 4; ++i) {
      const int r   = w * 8 + i;
      const int key = ((r & 15) << 1) | ((r >> 3) & 1);
      const float* src =
          adj + (size_t)(row0 + r) * NROW + t * 256 + ((lane ^ key) << 2);
      __builtin_amdgcn_global_load_lds(
          (const __attribute__((address_space(1))) void*)src,
          (__attribute__((address_space(3))) void*)(&LdsA[buf][r * 1024]),
          16, 0, 2 /* NT */);
    }
  };
  // --- A reg half: rows 4..7; linear NT loads, swizzle applied at ds_write.
  v4f areg[4];               // 16 VGPR
  auto issue_a_reg = [&](int t) {
#pragma unroll
    for (int i = 0; i < 4; ++i) {
      const int r = w * 8 + 4 + i;
      const float* src =
          adj + (size_t)(row0 + r) * NROW + t * 256 + (lane << 2);
      areg[i] = __builtin_nontemporal_load((const v4f*)src);
    }
  };
  auto write_a_reg = [&](int buf) {
#pragma unroll
    for (int i = 0; i < 4; ++i) {
      const int r   = w * 8 + 4 + i;
      const int key = ((r & 15) << 1) | ((r >> 3) & 1);
      *(v4f*)(&LdsA[buf][r * 1024 + ((lane ^ key) << 4)]) = areg[i];
    }
  };

  // --- B half-tile: [4 kg][2 ci] = 32 VGPR per set (col-dedup'd).
  const __bf16* __restrict__ Bpw = Bp + ((size_t)(w * 2) * 64 + lane) * 8;
  auto issue_b = [&](int half, v8bf (&b)[4][2]) {
#pragma unroll
    for (int g = 0; g < 4; ++g)
#pragma unroll
      for (int ci = 0; ci < 2; ++ci)
        b[g][ci] = *(const v8bf*)(
            Bpw + ((size_t)((half * 4 + g) * 16 + ci)) * 512);
  };

  auto compute_half = [&](int buf, int h, v8bf (&b)[4][2]) {
    const char* ab = &LdsA[buf][0];
#pragma unroll
    for (int g = 0; g < 4; ++g) {
      const int kg = h * 4 + g;
      v8bf af[4];
#pragma unroll
      for (int rt = 0; rt < 4; ++rt) {
        const int r   = rt * 16 + llo;
        const int key = ((r & 15) << 1) | ((r >> 3) & 1);
        const char* base = ab + r * 1024;
        v4f u0 = *(const v4f*)(base + (((kg * 8 + lhi * 2    ) ^ key) << 4));
        v4f u1 = *(const v4f*)(base + (((kg * 8 + lhi * 2 + 1) ^ key) << 4));
        af[rt] = cvt_bf8(u0, u1);
      }
#pragma unroll
      for (int ci = 0; ci < 2; ++ci)
#pragma unroll
        for (int rt = 0; rt < 4; ++rt)
          acc[rt][ci] = __builtin_amdgcn_mfma_f32_16x16x32_bf16(
              af[rt], b[g][ci], acc[rt][ci], 0, 0, 0);
    }
  };

  v8bf bX[4][2], bY[4][2];

  // prologue -- FIFO: dma0(4), regA0(4), b0(8), b1(8), dma1(4) = 28 issued;
  // vmcnt(20) retires dma0+regA0; write reg half of A(0); publish buf0.
  stage_a_dma(0, 0);
  issue_a_reg(0);
  __builtin_amdgcn_sched_barrier(0);
  issue_b(0, bX);
  __builtin_amdgcn_sched_barrier(0);
  issue_b(1, bY);
  __builtin_amdgcn_sched_barrier(0);
  stage_a_dma(1, 1);
  asm volatile("s_waitcnt vmcnt(20)" ::: "memory");
  __builtin_amdgcn_sched_barrier(0);
  write_a_reg(0);
  asm volatile("s_waitcnt lgkmcnt(0)" ::: "memory");
  __builtin_amdgcn_sched_barrier(0);
  __builtin_amdgcn_s_barrier();

#pragma unroll 1
  for (int t = 0; t < NSTEP; ++t) {
    const int p = t & 1;
    {
      const int tn = (t + 1 < NSTEP) ? t + 1 : NSTEP - 1;
      issue_a_reg(tn);                      // reg half of A(t+1), step-top
    }
    __builtin_amdgcn_sched_barrier(0);
    compute_half(p, 0, bX);                 // waits bX only (landed long ago)
    __builtin_amdgcn_sched_barrier(0);
    {
      const int hb = (2 * t + 2 < 2 * NSTEP) ? 2 * t + 2 : 2 * NSTEP - 2;
      issue_b(hb, bX);
    }
    __builtin_amdgcn_sched_barrier(0);
    compute_half(p, 1, bY);
    __builtin_amdgcn_sched_barrier(0);
    {
      const int hb = (2 * t + 3 < 2 * NSTEP) ? 2 * t + 3 : 2 * NSTEP - 1;
      issue_b(hb, bY);
    }
    __builtin_amdgcn_sched_barrier(0);
    __builtin_amdgcn_s_barrier();           // buf[p] fully consumed
    {
      const int ta = (t + 2 < NSTEP) ? t + 2 : NSTEP - 1;
      stage_a_dma(p, ta);                   // dma half of A(t+2) into buf[p]
    }
    // retire regA(t+1)+dmaA(t+1): newer = bX'(8)+bY'(8)+dmaA(t+2)(4) = 20
    asm volatile("s_waitcnt vmcnt(20)" ::: "memory");
    __builtin_amdgcn_sched_barrier(0);
    write_a_reg(p ^ 1);                     // reg half of A(t+1) -> buf[p^1]
    asm volatile("s_waitcnt lgkmcnt(0)" ::: "memory");
    __builtin_amdgcn_sched_barrier(0);
    __builtin_amdgcn_s_barrier();           // buf[p^1] = A(t+1) ready
  }
  asm volatile("s_waitcnt vmcnt(0)" ::: "memory");  // retire clamped dups

  // epilogue: bias + prelu, direct store
  const float slope = prelu_a[0];
  float* __restrict__ outp = out + (size_t)z * M_ELEM;
#pragma unroll
  for (int ci = 0; ci < 2; ++ci) {
    const int o  = w * 32 + ci * 16 + llo;
    const float bs = bias[o];
#pragma unroll
    for (int rt = 0; rt < 4; ++rt) {
      const int m = row0 + rt * 16 + lhi * 4;
#pragma unroll
      for (int r = 0; r < 4; ++r) {
        float v = acc[rt][ci][r] + bs;
        outp[(size_t)(m + r) * OUTF + o] = v >= 0.f ? v : slope * v;
      }
    }
  }
}

extern "C" void kernel_launch(void* const* d_in, const int* in_sizes, int n_in,
                              void* d_out, int out_size, void* d_ws, size_t ws_size,
                              hipStream_t stream) {
  const float* feat = (const float*)d_in[0];
  const float* adj  = (const float*)d_in[1];
  const float* aug  = (const float*)d_in[2];
  const float* W    = (const float*)d_in[3];
  const float* bias = (const float*)d_in[4];
  const float* pa   = (const float*)d_in[5];
  float* out = (float*)d_out;
  __bf16* Bp = (__bf16*)d_ws;                    // 4 MB packed seq_fts

  seq_fts_kernel<<<dim3(NROW / 64), 256, 0, stream>>>(feat, W, Bp);
  gcn_agg_kernel<<<dim3(NROW / 64, 2), 512, 0, stream>>>(
      adj, aug, Bp, bias, pa, out);
}